// Round 1
// baseline (453.698 us; speedup 1.0000x reference)
//
#include <hip/hip_runtime.h>
#include <cmath>

#define Bn  8
#define Tn  2048
#define Cn  1024
#define Hn  64
#define BTn 16384  // Bn*Tn

// ---------------------------------------------------------------------------
// Kernel 1: fused QKV projection + RoPE.
// grid = BTn/8 blocks, block = 192 threads (3 waves: wave0->Q, wave1->K, wave2->V)
// Each block: stage 8 rows of x in LDS; lane = output head dim h (0..63);
// each wave computes 8 rows x 64 cols of its projection.
// ---------------------------------------------------------------------------
__global__ __launch_bounds__(192) void proj_rope_kernel(
    const float* __restrict__ x,  const float* __restrict__ Wq,
    const float* __restrict__ Wk, const float* __restrict__ Wv,
    float* __restrict__ qws, float* __restrict__ kws, float* __restrict__ vws)
{
    __shared__ float xs[8 * Cn];          // 32 KB, natural [r][c] layout
    const int tid  = threadIdx.x;
    const int row0 = blockIdx.x * 8;      // global row (b*T + t), never straddles batch

    // Stage 8 rows (8192 floats = 2048 float4) coalesced, conflict-free b128 writes.
    const float4* xg4 = (const float4*)(x + (size_t)row0 * Cn);
    float4* xs4 = (float4*)xs;
    #pragma unroll
    for (int j = 0; j < 11; j++) {
        int idx = tid + j * 192;
        if (idx < 2048) xs4[idx] = xg4[idx];
    }
    __syncthreads();

    const int wave = tid >> 6;
    const int lane = tid & 63;
    const float* __restrict__ W = (wave == 0) ? Wq : (wave == 1) ? Wk : Wv;

    float acc[8];
    #pragma unroll
    for (int r = 0; r < 8; r++) acc[r] = 0.0f;

    // Main dot-product loop: 4 W loads (coalesced, L2-hit) + 8 broadcast b128 LDS
    // reads + 32 fma per 4 columns of C.
    for (int c = 0; c < Cn; c += 4) {
        float w0 = W[(c + 0) * Hn + lane];
        float w1 = W[(c + 1) * Hn + lane];
        float w2 = W[(c + 2) * Hn + lane];
        float w3 = W[(c + 3) * Hn + lane];
        #pragma unroll
        for (int r = 0; r < 8; r++) {
            float4 xv = xs4[(r * Cn + c) >> 2];   // broadcast: all lanes same addr
            acc[r] = fmaf(xv.x, w0, acc[r]);
            acc[r] = fmaf(xv.y, w1, acc[r]);
            acc[r] = fmaf(xv.z, w2, acc[r]);
            acc[r] = fmaf(xv.w, w3, acc[r]);
        }
    }

    float* __restrict__ outp = (wave == 0) ? qws : (wave == 1) ? kws : vws;
    if (wave < 2) {
        // RoPE: pairs (2i, 2i+1), angle = t * 10000^{-i/32}
        const float fi   = (float)(lane >> 1);
        const float invf = __expf(-0.28782313662425572f * fi); // ln(10000)/32
        #pragma unroll
        for (int r = 0; r < 8; r++) {
            float partner = __shfl_xor(acc[r], 1, 64);
            int   t   = (row0 + r) & (Tn - 1);
            float ang = (float)t * invf;
            float cv  = cosf(ang);
            float sv  = sinf(ang);
            // even lane (2i):   x0*cos - x1*sin ; odd lane (2i+1): x1*cos + x0*sin
            float val = (lane & 1) ? fmaf(acc[r], cv,  partner * sv)
                                   : fmaf(acc[r], cv, -partner * sv);
            outp[(size_t)(row0 + r) * Hn + lane] = val;
        }
    } else {
        #pragma unroll
        for (int r = 0; r < 8; r++)
            outp[(size_t)(row0 + r) * Hn + lane] = acc[r];
    }
}

// ---------------------------------------------------------------------------
// Kernel 2: causal flash attention (fp32).
// grid = 512 blocks: qt = 63 - blk/8 (longest-first), b = blk%8.
// Q-tile = 32 rows, S-tile = 64 rows, block = 256 threads.
// Thread (ty,tx) = (tid/16, tid%16) owns a 2x4 register tile:
//   rows r = ty*2+a, score cols s = tx*4+b2, out cols h = tx*4+b2.
// LDS row stride 65 keeps all inner-loop ds_read_b32 at <=2-way conflicts.
// ---------------------------------------------------------------------------
#define QT  32
#define STL 64
#define LDP 65

__global__ __launch_bounds__(256) void attn_kernel(
    const float* __restrict__ qws, const float* __restrict__ kws,
    const float* __restrict__ vws, float* __restrict__ out)
{
    __shared__ float qs[QT  * LDP];
    __shared__ float ks[STL * LDP];
    __shared__ float vs[STL * LDP];
    __shared__ float ps[QT  * LDP];

    const int blk = blockIdx.x;
    const int qt  = 63 - (blk >> 3);   // longest work first (LPT scheduling)
    const int b   = blk & 7;
    const int t0  = qt * QT;
    const int tid = threadIdx.x;
    const int ty  = tid >> 4;          // 0..15
    const int tx  = tid & 15;          // 0..15

    const float* __restrict__ qb = qws + (size_t)b * Tn * Hn;
    const float* __restrict__ kb = kws + (size_t)b * Tn * Hn;
    const float* __restrict__ vb = vws + (size_t)b * Tn * Hn;

    // Stage Q tile (32x64 = 512 float4, 2 per thread)
    {
        const float4* qg = (const float4*)(qb + (size_t)t0 * Hn);
        #pragma unroll
        for (int j = 0; j < 2; j++) {
            int idx4 = tid + j * 256;
            int r  = idx4 >> 4;
            int h4 = (idx4 & 15) << 2;
            float4 v = qg[idx4];
            qs[r * LDP + h4 + 0] = v.x;
            qs[r * LDP + h4 + 1] = v.y;
            qs[r * LDP + h4 + 2] = v.z;
            qs[r * LDP + h4 + 3] = v.w;
        }
    }

    float m_run[2] = {-1e30f, -1e30f};
    float l_run[2] = {0.0f, 0.0f};
    float o[2][4];
    #pragma unroll
    for (int a = 0; a < 2; a++)
        #pragma unroll
        for (int c = 0; c < 4; c++) o[a][c] = 0.0f;

    const int nst = (t0 + QT - 1) / STL + 1;   // s-tiles covering s <= t0+QT-1

    for (int jt = 0; jt < nst; jt++) {
        const int s0 = jt * STL;
        __syncthreads();   // previous iteration done reading ks/vs/ps

        // Stage K and V tiles (each 64x64 = 1024 float4, 4 per thread)
        const float4* kg = (const float4*)(kb + (size_t)s0 * Hn);
        const float4* vg = (const float4*)(vb + (size_t)s0 * Hn);
        #pragma unroll
        for (int j = 0; j < 4; j++) {
            int idx4 = tid + j * 256;
            int r  = idx4 >> 4;
            int h4 = (idx4 & 15) << 2;
            float4 kv = kg[idx4];
            ks[r * LDP + h4 + 0] = kv.x;
            ks[r * LDP + h4 + 1] = kv.y;
            ks[r * LDP + h4 + 2] = kv.z;
            ks[r * LDP + h4 + 3] = kv.w;
            float4 vv = vg[idx4];
            vs[r * LDP + h4 + 0] = vv.x;
            vs[r * LDP + h4 + 1] = vv.y;
            vs[r * LDP + h4 + 2] = vv.z;
            vs[r * LDP + h4 + 3] = vv.w;
        }
        __syncthreads();

        // S = Q K^T for this tile pair: 2x4 per thread, dot over h
        float sv[2][4];
        #pragma unroll
        for (int a = 0; a < 2; a++)
            #pragma unroll
            for (int c = 0; c < 4; c++) sv[a][c] = 0.0f;

        #pragma unroll 4
        for (int h = 0; h < Hn; h++) {
            float q0 = qs[(ty * 2 + 0) * LDP + h];
            float q1 = qs[(ty * 2 + 1) * LDP + h];
            float k0 = ks[(tx * 4 + 0) * LDP + h];
            float k1 = ks[(tx * 4 + 1) * LDP + h];
            float k2 = ks[(tx * 4 + 2) * LDP + h];
            float k3 = ks[(tx * 4 + 3) * LDP + h];
            sv[0][0] = fmaf(q0, k0, sv[0][0]);
            sv[0][1] = fmaf(q0, k1, sv[0][1]);
            sv[0][2] = fmaf(q0, k2, sv[0][2]);
            sv[0][3] = fmaf(q0, k3, sv[0][3]);
            sv[1][0] = fmaf(q1, k0, sv[1][0]);
            sv[1][1] = fmaf(q1, k1, sv[1][1]);
            sv[1][2] = fmaf(q1, k2, sv[1][2]);
            sv[1][3] = fmaf(q1, k3, sv[1][3]);
        }

        // Online softmax per row (reduce across the 16 tx lanes of the row group)
        float pv[2][4];
        #pragma unroll
        for (int a = 0; a < 2; a++) {
            const int tg = t0 + ty * 2 + a;
            float mx = -1e30f;
            #pragma unroll
            for (int b2 = 0; b2 < 4; b2++) {
                int sg = s0 + tx * 4 + b2;
                float val = sv[a][b2] * 0.125f;       // H^{-1/2}
                if (sg > tg) val = -1e30f;            // causal mask
                sv[a][b2] = val;
                mx = fmaxf(mx, val);
            }
            #pragma unroll
            for (int off = 1; off < 16; off <<= 1)
                mx = fmaxf(mx, __shfl_xor(mx, off, 64));
            float mnew  = fmaxf(m_run[a], mx);
            float alpha = __expf(m_run[a] - mnew);
            m_run[a] = mnew;
            float rs = 0.0f;
            #pragma unroll
            for (int b2 = 0; b2 < 4; b2++) {
                float p = __expf(sv[a][b2] - mnew);   // masked -> exp(-1e30) = 0
                pv[a][b2] = p;
                rs += p;
            }
            #pragma unroll
            for (int off = 1; off < 16; off <<= 1)
                rs += __shfl_xor(rs, off, 64);
            l_run[a] = fmaf(l_run[a], alpha, rs);
            o[a][0] *= alpha; o[a][1] *= alpha; o[a][2] *= alpha; o[a][3] *= alpha;
        }

        // P to LDS for the PV GEMM
        #pragma unroll
        for (int a = 0; a < 2; a++)
            #pragma unroll
            for (int b2 = 0; b2 < 4; b2++)
                ps[(ty * 2 + a) * LDP + tx * 4 + b2] = pv[a][b2];
        __syncthreads();

        // O += P V : thread owns rows ty*2+a, out cols tx*4+b2
        #pragma unroll 4
        for (int s = 0; s < STL; s++) {
            float p0 = ps[(ty * 2 + 0) * LDP + s];
            float p1 = ps[(ty * 2 + 1) * LDP + s];
            float v0 = vs[s * LDP + tx * 4 + 0];
            float v1 = vs[s * LDP + tx * 4 + 1];
            float v2 = vs[s * LDP + tx * 4 + 2];
            float v3 = vs[s * LDP + tx * 4 + 3];
            o[0][0] = fmaf(p0, v0, o[0][0]);
            o[0][1] = fmaf(p0, v1, o[0][1]);
            o[0][2] = fmaf(p0, v2, o[0][2]);
            o[0][3] = fmaf(p0, v3, o[0][3]);
            o[1][0] = fmaf(p1, v0, o[1][0]);
            o[1][1] = fmaf(p1, v1, o[1][1]);
            o[1][2] = fmaf(p1, v2, o[1][2]);
            o[1][3] = fmaf(p1, v3, o[1][3]);
        }
    }

    // Epilogue: normalize and store (coalesced float4 per row group)
    #pragma unroll
    for (int a = 0; a < 2; a++) {
        float inv = 1.0f / l_run[a];
        int tg = t0 + ty * 2 + a;
        float4 res;
        res.x = o[a][0] * inv;
        res.y = o[a][1] * inv;
        res.z = o[a][2] * inv;
        res.w = o[a][3] * inv;
        ((float4*)(out + ((size_t)b * Tn + tg) * Hn))[tx] = res;
    }
}

extern "C" void kernel_launch(void* const* d_in, const int* in_sizes, int n_in,
                              void* d_out, int out_size, void* d_ws, size_t ws_size,
                              hipStream_t stream) {
    const float* x  = (const float*)d_in[0];
    const float* Wq = (const float*)d_in[1];
    const float* Wk = (const float*)d_in[2];
    const float* Wv = (const float*)d_in[3];

    float* qws = (float*)d_ws;                    // [BTn][Hn]
    float* kws = qws + (size_t)BTn * Hn;          // [BTn][Hn]
    float* vws = kws + (size_t)BTn * Hn;          // [BTn][Hn]
    float* outp = (float*)d_out;

    proj_rope_kernel<<<BTn / 8, 192, 0, stream>>>(x, Wq, Wk, Wv, qws, kws, vws);
    attn_kernel<<<512, 256, 0, stream>>>(qws, kws, vws, outp);
}

// Round 2
// 205.469 us; speedup vs baseline: 2.2081x; 2.2081x over previous
//
#include <hip/hip_runtime.h>
#include <cmath>

#define Tn  2048
#define Cn  1024
#define Hn  64
#define BTn 16384

typedef _Float16 f16x8 __attribute__((ext_vector_type(8)));
typedef _Float16 f16x2 __attribute__((ext_vector_type(2)));
typedef float    f32x4 __attribute__((ext_vector_type(4)));

// ---------------------------------------------------------------------------
// prep: transpose Wq|Wk|Wv (each [Cn][64] fp32) into Wt[192][Cn] f16
// ---------------------------------------------------------------------------
__global__ __launch_bounds__(256) void prep_w_kernel(
    const float* __restrict__ Wq, const float* __restrict__ Wk,
    const float* __restrict__ Wv, _Float16* __restrict__ Wt)
{
    __shared__ float ts[64][65];
    const int blk = blockIdx.x;          // 48 = 3 proj * 16 c-tiles
    const int p   = blk >> 4;
    const int c0  = (blk & 15) * 64;
    const float* __restrict__ W = (p == 0) ? Wq : (p == 1) ? Wk : Wv;
    const int tid = threadIdx.x;
    #pragma unroll
    for (int it = 0; it < 16; it++) {
        int idx = tid + it * 256;        // 4096 elems
        int c = idx >> 6, n = idx & 63;
        ts[c][n] = W[(size_t)(c0 + c) * Hn + n];   // coalesced read
    }
    __syncthreads();
    #pragma unroll
    for (int it = 0; it < 16; it++) {
        int idx = tid + it * 256;
        int n = idx >> 6, c = idx & 63;
        Wt[(size_t)(p * 64 + n) * Cn + c0 + c] = (_Float16)ts[c][n];
    }
}

// ---------------------------------------------------------------------------
// proj: x[16384][1024] @ W -> q,k (RoPE, q pre-scaled by H^-1/2) and v, all f16.
// grid = 768 blocks: pid%3 = proj, pid/3 = 64-row m-slab. 256 thr = 4 waves
// in a 2x2 wave grid; each wave: 2 m-tiles x 2 n-tiles of 16x16x32 MFMA.
// ---------------------------------------------------------------------------
__global__ __launch_bounds__(256) void proj_kernel(
    const float* __restrict__ x, const _Float16* __restrict__ Wt,
    _Float16* __restrict__ qh, _Float16* __restrict__ kh, _Float16* __restrict__ vh)
{
    __shared__ _Float16 xsld[64 * 40];   // [m][k] stride 40 (80B rows: 2-way-free frags)
    __shared__ _Float16 wsld[64 * 40];   // [n][k]
    const int pid  = blockIdx.x;
    const int p    = pid % 3;
    const int row0 = (pid / 3) * 64;     // never straddles a batch (64 | 2048)
    const int tid  = threadIdx.x;
    const int wave = tid >> 6, lane = tid & 63;
    const int quad = lane >> 4, l15 = lane & 15;
    const int wr = wave >> 1, wc = wave & 1;
    const int sm  = tid >> 2;            // staging row 0..63
    const int sc8 = (tid & 3) * 8;       // staging k-offset 0,8,16,24

    const float*    __restrict__ xg = x  + (size_t)row0 * Cn;
    const _Float16* __restrict__ wg = Wt + (size_t)p * 64 * Cn;

    f32x4 acc[2][2] = {};

    for (int kc = 0; kc < Cn; kc += 32) {
        float4 a0 = *(const float4*)&xg[(size_t)sm * Cn + kc + sc8];
        float4 a1 = *(const float4*)&xg[(size_t)sm * Cn + kc + sc8 + 4];
        f16x8 xv = { (_Float16)a0.x, (_Float16)a0.y, (_Float16)a0.z, (_Float16)a0.w,
                     (_Float16)a1.x, (_Float16)a1.y, (_Float16)a1.z, (_Float16)a1.w };
        f16x8 wv = *(const f16x8*)&wg[(size_t)sm * Cn + kc + sc8];
        __syncthreads();                 // prev iter frag reads done
        *(f16x8*)&xsld[sm * 40 + sc8] = xv;
        *(f16x8*)&wsld[sm * 40 + sc8] = wv;
        __syncthreads();

        f16x8 af0 = *(const f16x8*)&xsld[(wr * 32 +      l15) * 40 + quad * 8];
        f16x8 af1 = *(const f16x8*)&xsld[(wr * 32 + 16 + l15) * 40 + quad * 8];
        f16x8 bf0 = *(const f16x8*)&wsld[(wc * 32 +      l15) * 40 + quad * 8];
        f16x8 bf1 = *(const f16x8*)&wsld[(wc * 32 + 16 + l15) * 40 + quad * 8];
        acc[0][0] = __builtin_amdgcn_mfma_f32_16x16x32_f16(af0, bf0, acc[0][0], 0, 0, 0);
        acc[0][1] = __builtin_amdgcn_mfma_f32_16x16x32_f16(af0, bf1, acc[0][1], 0, 0, 0);
        acc[1][0] = __builtin_amdgcn_mfma_f32_16x16x32_f16(af1, bf0, acc[1][0], 0, 0, 0);
        acc[1][1] = __builtin_amdgcn_mfma_f32_16x16x32_f16(af1, bf1, acc[1][1], 0, 0, 0);
    }

    // Epilogue: RoPE for q/k (pairs (2i,2i+1) = adjacent lanes), pack f16x2, store.
    _Float16* __restrict__ outb = (p == 0) ? qh : (p == 1) ? kh : vh;
    float invf[2];
    #pragma unroll
    for (int nt = 0; nt < 2; nt++) {
        int h = wc * 32 + nt * 16 + l15;
        invf[nt] = __expf(-0.2878231366242557f * (float)(h >> 1)); // 10000^{-i/32}
    }
    #pragma unroll
    for (int mt = 0; mt < 2; mt++) {
        #pragma unroll
        for (int nt = 0; nt < 2; nt++) {
            const int h = wc * 32 + nt * 16 + l15;
            #pragma unroll
            for (int r = 0; r < 4; r++) {
                float val = acc[mt][nt][r];
                int row = row0 + wr * 32 + mt * 16 + quad * 4 + r;  // b*T + t
                float res;
                if (p < 2) {
                    float partner = __shfl_xor(val, 1, 64);
                    float ang = (float)(row & (Tn - 1)) * invf[nt];
                    float sv, cv;
                    __sincosf(ang, &sv, &cv);
                    res = (h & 1) ? fmaf(val, cv, partner * sv)
                                  : fmaf(val, cv, -partner * sv);
                    if (p == 0) res *= 0.125f;     // fold H^{-1/2} into q
                } else {
                    res = val;
                }
                float resn = __shfl_xor(res, 1, 64);
                if (!(l15 & 1)) {
                    f16x2 pk = { (_Float16)res, (_Float16)resn };
                    *(f16x2*)&outb[(size_t)row * Hn + h] = pk;
                }
            }
        }
    }
}

// ---------------------------------------------------------------------------
// attn: MFMA flash attention. QT=32, STL=64, 128 thr (2 waves), grid 512 (LPT).
// Wave w owns q-rows [w*16, w*16+16). QK^T: A=q rows, B=k rows (no transpose).
// V staged XOR-swizzle-transposed; P f16 round-trip through wave-private ps.
// ---------------------------------------------------------------------------
#define SQP 72   // LDS row stride in f16 (144 B): 2-way-free frag reads

__global__ __launch_bounds__(128) void attn_kernel(
    const _Float16* __restrict__ qh, const _Float16* __restrict__ kh,
    const _Float16* __restrict__ vh, float* __restrict__ out)
{
    __shared__ _Float16 qs [32 * SQP];
    __shared__ _Float16 ks [64 * SQP];
    __shared__ _Float16 vsT[64 * SQP];
    __shared__ _Float16 ps [32 * SQP];

    const int blk = blockIdx.x;
    const int qt  = 63 - (blk >> 3);     // longest first
    const int b   = blk & 7;
    const int t0  = qt * 32;
    const int tid = threadIdx.x;
    const int w = tid >> 6, lane = tid & 63;
    const int quad = lane >> 4, l15 = lane & 15;

    const _Float16* __restrict__ qg = qh + (size_t)b * Tn * Hn;
    const _Float16* __restrict__ kg = kh + (size_t)b * Tn * Hn;
    const _Float16* __restrict__ vg = vh + (size_t)b * Tn * Hn;

    #pragma unroll
    for (int it = 0; it < 2; it++) {
        int idx = tid + it * 128;        // 256 chunks of 8
        int m = idx >> 3, h0 = (idx & 7) * 8;
        *(f16x8*)&qs[m * SQP + h0] = *(const f16x8*)&qg[(size_t)(t0 + m) * Hn + h0];
    }

    float m_run[4], l_run[4];
    f32x4 oacc[4] = {};
    #pragma unroll
    for (int r = 0; r < 4; r++) { m_run[r] = -1e30f; l_run[r] = 0.0f; }

    const int nst = ((t0 + 31) >> 6) + 1;
    for (int jt = 0; jt < nst; jt++) {
        const int s0 = jt * 64;
        __syncthreads();                 // prev iter reads done (also covers qs staging)
        #pragma unroll
        for (int it = 0; it < 4; it++) {
            int idx = tid + it * 128;    // 512 chunks of 8
            int s = idx >> 3, h0 = (idx & 7) * 8;
            *(f16x8*)&ks[s * SQP + h0] = *(const f16x8*)&kg[(size_t)(s0 + s) * Hn + h0];
            f16x8 vv = *(const f16x8*)&vg[(size_t)(s0 + s) * Hn + h0];
            int xb = ((s >> 3) ^ (h0 >> 3)) << 3;   // XOR swizzle: conflict-free T
            int sl = s & 7;
            #pragma unroll
            for (int j = 0; j < 8; j++)
                vsT[(h0 + j) * SQP + xb + sl] = vv[j];
        }
        __syncthreads();

        // S = Q K^T  (16 rows x 64 cols per wave, 8 MFMA)
        f16x8 aq0 = *(const f16x8*)&qs[(w * 16 + l15) * SQP +      quad * 8];
        f16x8 aq1 = *(const f16x8*)&qs[(w * 16 + l15) * SQP + 32 + quad * 8];
        f32x4 sacc[4];
        #pragma unroll
        for (int nt = 0; nt < 4; nt++) {
            f16x8 b0 = *(const f16x8*)&ks[(nt * 16 + l15) * SQP +      quad * 8];
            f16x8 b1 = *(const f16x8*)&ks[(nt * 16 + l15) * SQP + 32 + quad * 8];
            f32x4 z = {};
            z = __builtin_amdgcn_mfma_f32_16x16x32_f16(aq0, b0, z, 0, 0, 0);
            z = __builtin_amdgcn_mfma_f32_16x16x32_f16(aq1, b1, z, 0, 0, 0);
            sacc[nt] = z;
        }

        if (jt == nst - 1) {             // causal mask, last s-tile only
            #pragma unroll
            for (int nt = 0; nt < 4; nt++)
                #pragma unroll
                for (int r = 0; r < 4; r++) {
                    int scol = s0 + nt * 16 + l15;
                    int trow = t0 + w * 16 + quad * 4 + r;
                    if (scol > trow) sacc[nt][r] = -1e30f;
                }
        }

        // online softmax (rows = quad*4+r; reduce across the 16 lanes of the quad)
        float pr[4][4];
        #pragma unroll
        for (int r = 0; r < 4; r++) {
            float mx = fmaxf(fmaxf(sacc[0][r], sacc[1][r]),
                             fmaxf(sacc[2][r], sacc[3][r]));
            #pragma unroll
            for (int off = 1; off < 16; off <<= 1)
                mx = fmaxf(mx, __shfl_xor(mx, off, 64));
            float mnew  = fmaxf(m_run[r], mx);
            float alpha = __expf(m_run[r] - mnew);
            m_run[r] = mnew;
            float rs = 0.0f;
            #pragma unroll
            for (int nt = 0; nt < 4; nt++) {
                float pv = __expf(sacc[nt][r] - mnew);
                pr[nt][r] = pv; rs += pv;
            }
            #pragma unroll
            for (int off = 1; off < 16; off <<= 1)
                rs += __shfl_xor(rs, off, 64);
            l_run[r] = fmaf(l_run[r], alpha, rs);
            #pragma unroll
            for (int ht = 0; ht < 4; ht++)
                oacc[ht][r] = oacc[ht][r] * alpha;
        }

        // P -> ps (f16, wave-private rows; same-wave RAW -> no barrier needed)
        #pragma unroll
        for (int nt = 0; nt < 4; nt++)
            #pragma unroll
            for (int r = 0; r < 4; r++) {
                float pv = pr[nt][r];
                float pn = __shfl_xor(pv, 1, 64);
                if (!(l15 & 1)) {
                    f16x2 pk = { (_Float16)pv, (_Float16)pn };
                    *(f16x2*)&ps[(w * 16 + quad * 4 + r) * SQP + nt * 16 + l15] = pk;
                }
            }

        // O += P V  (8 MFMA)
        #pragma unroll
        for (int sc = 0; sc < 2; sc++) {
            f16x8 ap = *(const f16x8*)&ps[(w * 16 + l15) * SQP + sc * 32 + quad * 8];
            #pragma unroll
            for (int ht = 0; ht < 4; ht++) {
                int h  = ht * 16 + l15;
                int sq = sc * 32 + quad * 8;
                f16x8 bv = *(const f16x8*)&vsT[h * SQP + (((sq >> 3) ^ (h >> 3)) << 3)];
                oacc[ht] = __builtin_amdgcn_mfma_f32_16x16x32_f16(ap, bv, oacc[ht], 0, 0, 0);
            }
        }
    }

    #pragma unroll
    for (int r = 0; r < 4; r++) {
        float inv  = 1.0f / l_run[r];
        int   trow = t0 + w * 16 + quad * 4 + r;
        float* op  = out + ((size_t)b * Tn + trow) * Hn;
        #pragma unroll
        for (int ht = 0; ht < 4; ht++)
            op[ht * 16 + l15] = oacc[ht][r] * inv;
    }
}

extern "C" void kernel_launch(void* const* d_in, const int* in_sizes, int n_in,
                              void* d_out, int out_size, void* d_ws, size_t ws_size,
                              hipStream_t stream) {
    const float* x  = (const float*)d_in[0];
    const float* Wq = (const float*)d_in[1];
    const float* Wk = (const float*)d_in[2];
    const float* Wv = (const float*)d_in[3];

    const size_t qkvN = (size_t)BTn * Hn;         // 1M f16 elems each
    _Float16* qh = (_Float16*)d_ws;
    _Float16* kh = qh + qkvN;
    _Float16* vh = kh + qkvN;
    _Float16* Wt = vh + qkvN;                     // [192][1024]

    prep_w_kernel<<<48, 256, 0, stream>>>(Wq, Wk, Wv, Wt);
    proj_kernel<<<768, 256, 0, stream>>>(x, Wt, qh, kh, vh);
    attn_kernel<<<512, 128, 0, stream>>>(qh, kh, vh, (float*)d_out);
}

// Round 3
// 190.443 us; speedup vs baseline: 2.3823x; 1.0789x over previous
//
#include <hip/hip_runtime.h>
#include <cmath>

#define Tn  2048
#define Cn  1024
#define Hn  64
#define BTn 16384

typedef _Float16 f16x8 __attribute__((ext_vector_type(8)));
typedef _Float16 f16x4 __attribute__((ext_vector_type(4)));
typedef _Float16 f16x2 __attribute__((ext_vector_type(2)));
typedef float    f32x4 __attribute__((ext_vector_type(4)));

// ---------------------------------------------------------------------------
// prep: transpose Wq|Wk|Wv (each [Cn][64] fp32) into Wt[192][Cn] f16
// ---------------------------------------------------------------------------
__global__ __launch_bounds__(256) void prep_w_kernel(
    const float* __restrict__ Wq, const float* __restrict__ Wk,
    const float* __restrict__ Wv, _Float16* __restrict__ Wt)
{
    __shared__ float ts[64][65];
    const int blk = blockIdx.x;          // 48 = 3 proj * 16 c-tiles
    const int p   = blk >> 4;
    const int c0  = (blk & 15) * 64;
    const float* __restrict__ W = (p == 0) ? Wq : (p == 1) ? Wk : Wv;
    const int tid = threadIdx.x;
    #pragma unroll
    for (int it = 0; it < 16; it++) {
        int idx = tid + it * 256;
        int c = idx >> 6, n = idx & 63;
        ts[c][n] = W[(size_t)(c0 + c) * Hn + n];
    }
    __syncthreads();
    #pragma unroll
    for (int it = 0; it < 16; it++) {
        int idx = tid + it * 256;
        int n = idx >> 6, c = idx & 63;
        Wt[(size_t)(p * 64 + n) * Cn + c0 + c] = (_Float16)ts[c][n];
    }
}

// ---------------------------------------------------------------------------
// proj: unified QKV. Block = 32 rows of x vs all N=192 output cols (q|k|v).
// 256 thr = 4 waves; wave w owns n-range [w*48, w*48+48) x 32 rows
// (2 m-tiles x 3 n-tiles of 16x16x32 MFMA, 12 MFMA/iter). BK=64, 16 iters,
// double-buffered LDS + register prefetch, ONE barrier per iter.
// x is read once per row (not 3x); Wt (384 KB) stays L2-resident.
// ---------------------------------------------------------------------------
__global__ __launch_bounds__(256) void proj_kernel(
    const float* __restrict__ x, const _Float16* __restrict__ Wt,
    _Float16* __restrict__ qh, _Float16* __restrict__ kh, _Float16* __restrict__ vh)
{
    __shared__ _Float16 xs[2][32 * 72];
    __shared__ _Float16 ws[2][192 * 72];
    const int row0 = blockIdx.x * 32;
    const int tid  = threadIdx.x;
    const int wave = tid >> 6, lane = tid & 63;
    const int quad = lane >> 4, l15 = lane & 15;

    const int xr_row = tid >> 3;          // 0..31
    const int xr_ko  = (tid & 7) * 8;     // k offset 0..56

    float4 xr0, xr1;
    f16x8  wr[6];

    auto prefetch = [&](int kc) {
        const float* xp = &x[(size_t)(row0 + xr_row) * Cn + kc + xr_ko];
        xr0 = *(const float4*)xp;
        xr1 = *(const float4*)(xp + 4);
        #pragma unroll
        for (int it = 0; it < 6; it++) {
            int idx = tid + it * 256;     // 1536 units: n(192) x ko(8)
            wr[it] = *(const f16x8*)&Wt[(size_t)(idx >> 3) * Cn + kc + (idx & 7) * 8];
        }
    };
    auto stage = [&](int buf) {
        f16x8 xv = { (_Float16)xr0.x, (_Float16)xr0.y, (_Float16)xr0.z, (_Float16)xr0.w,
                     (_Float16)xr1.x, (_Float16)xr1.y, (_Float16)xr1.z, (_Float16)xr1.w };
        *(f16x8*)&xs[buf][xr_row * 72 + xr_ko] = xv;
        #pragma unroll
        for (int it = 0; it < 6; it++) {
            int idx = tid + it * 256;
            *(f16x8*)&ws[buf][(idx >> 3) * 72 + (idx & 7) * 8] = wr[it];
        }
    };

    f32x4 acc[2][3] = {};

    prefetch(0);
    stage(0);
    __syncthreads();

    for (int ki = 0; ki < 16; ki++) {
        const int cur = ki & 1;
        if (ki < 15) prefetch((ki + 1) * 64);
        #pragma unroll
        for (int ks2 = 0; ks2 < 2; ks2++) {
            f16x8 a0 = *(const f16x8*)&xs[cur][(     l15) * 72 + ks2 * 32 + quad * 8];
            f16x8 a1 = *(const f16x8*)&xs[cur][(16 + l15) * 72 + ks2 * 32 + quad * 8];
            #pragma unroll
            for (int nt = 0; nt < 3; nt++) {
                f16x8 b = *(const f16x8*)&ws[cur][(wave * 48 + nt * 16 + l15) * 72
                                                  + ks2 * 32 + quad * 8];
                acc[0][nt] = __builtin_amdgcn_mfma_f32_16x16x32_f16(a0, b, acc[0][nt], 0, 0, 0);
                acc[1][nt] = __builtin_amdgcn_mfma_f32_16x16x32_f16(a1, b, acc[1][nt], 0, 0, 0);
            }
        }
        if (ki < 15) stage(cur ^ 1);
        __syncthreads();
    }

    // Epilogue: RoPE for q/k (adjacent-lane pairs), q pre-scaled by H^-1/2, f16 out.
    #pragma unroll
    for (int nt = 0; nt < 3; nt++) {
        const int n = wave * 48 + nt * 16 + l15;
        const int p = n >> 6;             // wave-uniform within nt
        const int h = n & 63;
        _Float16* __restrict__ outb = (p == 0) ? qh : (p == 1) ? kh : vh;
        const float invf = __expf(-0.2878231366242557f * (float)(h >> 1));
        #pragma unroll
        for (int mt = 0; mt < 2; mt++) {
            #pragma unroll
            for (int r = 0; r < 4; r++) {
                int   row = row0 + mt * 16 + quad * 4 + r;   // b*T + t
                float val = acc[mt][nt][r];
                float res;
                if (p < 2) {
                    float partner = __shfl_xor(val, 1, 64);
                    float ang = (float)(row & (Tn - 1)) * invf;
                    float sv, cv;
                    __sincosf(ang, &sv, &cv);
                    res = (h & 1) ? fmaf(val, cv,  partner * sv)
                                  : fmaf(val, cv, -partner * sv);
                    if (p == 0) res *= 0.125f;
                } else {
                    res = val;
                }
                float resn = __shfl_xor(res, 1, 64);
                if (!(l15 & 1)) {
                    f16x2 pk = { (_Float16)res, (_Float16)resn };
                    *(f16x2*)&outb[(size_t)row * Hn + h] = pk;
                }
            }
        }
    }
}

// ---------------------------------------------------------------------------
// attn: MFMA flash attention, double-buffered K/V with register prefetch.
// QT=32, STL=64, 128 thr (2 waves), grid 512 LPT. One barrier per s-tile.
// V staged transposed via packed f16x2 writes + XOR swizzle (2-way max).
// ---------------------------------------------------------------------------
#define SQP 72

__global__ __launch_bounds__(128) void attn_kernel(
    const _Float16* __restrict__ qh, const _Float16* __restrict__ kh,
    const _Float16* __restrict__ vh, float* __restrict__ out)
{
    __shared__ _Float16 qs [32 * SQP];
    __shared__ _Float16 ks [2][64 * SQP];
    __shared__ _Float16 vsT[2][64 * SQP];
    __shared__ _Float16 ps [32 * SQP];

    const int blk = blockIdx.x;
    const int qt  = 63 - (blk >> 3);     // longest first
    const int b   = blk & 7;
    const int t0  = qt * 32;
    const int tid = threadIdx.x;
    const int w = tid >> 6, lane = tid & 63;
    const int quad = lane >> 4, l15 = lane & 15;

    const _Float16* __restrict__ qg = qh + (size_t)b * Tn * Hn;
    const _Float16* __restrict__ kg = kh + (size_t)b * Tn * Hn;
    const _Float16* __restrict__ vg = vh + (size_t)b * Tn * Hn;

    #pragma unroll
    for (int it = 0; it < 2; it++) {
        int idx = tid + it * 128;
        int m = idx >> 3, h0 = (idx & 7) * 8;
        *(f16x8*)&qs[m * SQP + h0] = *(const f16x8*)&qg[(size_t)(t0 + m) * Hn + h0];
    }

    f16x8 kreg[4];
    f16x4 vreg[4][2];
    auto prefetch = [&](int s0) {
        #pragma unroll
        for (int it = 0; it < 4; it++) {
            int idx = tid + it * 128;
            kreg[it] = *(const f16x8*)&kg[(size_t)(s0 + (idx >> 3)) * Hn + (idx & 7) * 8];
            int sp = idx >> 4, hq = idx & 15;
            const _Float16* vp = &vg[(size_t)(s0 + 2 * sp) * Hn + 4 * hq];
            vreg[it][0] = *(const f16x4*)vp;
            vreg[it][1] = *(const f16x4*)(vp + Hn);
        }
    };
    auto stage = [&](int buf) {
        #pragma unroll
        for (int it = 0; it < 4; it++) {
            int idx = tid + it * 128;
            *(f16x8*)&ks[buf][(idx >> 3) * SQP + (idx & 7) * 8] = kreg[it];
            int sp = idx >> 4, hq = idx & 15;
            #pragma unroll
            for (int j = 0; j < 4; j++) {
                int h  = 4 * hq + j;
                int xb = (((sp >> 2) ^ (h >> 3)) << 3);
                f16x2 pk = { vreg[it][0][j], vreg[it][1][j] };
                *(f16x2*)&vsT[buf][h * SQP + xb + 2 * (sp & 3)] = pk;
            }
        }
    };

    prefetch(0);
    stage(0);
    __syncthreads();

    const f16x8 aq0 = *(const f16x8*)&qs[(w * 16 + l15) * SQP +      quad * 8];
    const f16x8 aq1 = *(const f16x8*)&qs[(w * 16 + l15) * SQP + 32 + quad * 8];

    float m_run[4], l_run[4];
    f32x4 oacc[4] = {};
    #pragma unroll
    for (int r = 0; r < 4; r++) { m_run[r] = -1e30f; l_run[r] = 0.0f; }

    const int nst = ((t0 + 31) >> 6) + 1;
    for (int jt = 0; jt < nst; jt++) {
        const int cur = jt & 1;
        const int s0  = jt * 64;
        if (jt + 1 < nst) prefetch((jt + 1) * 64);   // overlaps compute below

        // S = Q K^T  (16 rows x 64 cols per wave, 8 MFMA)
        f32x4 sacc[4];
        #pragma unroll
        for (int nt = 0; nt < 4; nt++) {
            f16x8 b0 = *(const f16x8*)&ks[cur][(nt * 16 + l15) * SQP +      quad * 8];
            f16x8 b1 = *(const f16x8*)&ks[cur][(nt * 16 + l15) * SQP + 32 + quad * 8];
            f32x4 z = {};
            z = __builtin_amdgcn_mfma_f32_16x16x32_f16(aq0, b0, z, 0, 0, 0);
            z = __builtin_amdgcn_mfma_f32_16x16x32_f16(aq1, b1, z, 0, 0, 0);
            sacc[nt] = z;
        }

        if (jt == nst - 1) {             // causal mask only on the last s-tile
            #pragma unroll
            for (int nt = 0; nt < 4; nt++)
                #pragma unroll
                for (int r = 0; r < 4; r++) {
                    int scol = s0 + nt * 16 + l15;
                    int trow = t0 + w * 16 + quad * 4 + r;
                    if (scol > trow) sacc[nt][r] = -1e30f;
                }
        }

        // online softmax (rows = quad*4+r; reduce across the 16 lanes of each quad)
        float pr[4][4];
        #pragma unroll
        for (int r = 0; r < 4; r++) {
            float mx = fmaxf(fmaxf(sacc[0][r], sacc[1][r]),
                             fmaxf(sacc[2][r], sacc[3][r]));
            #pragma unroll
            for (int off = 1; off < 16; off <<= 1)
                mx = fmaxf(mx, __shfl_xor(mx, off, 64));
            float mnew  = fmaxf(m_run[r], mx);
            float alpha = __expf(m_run[r] - mnew);
            m_run[r] = mnew;
            float rs = 0.0f;
            #pragma unroll
            for (int nt = 0; nt < 4; nt++) {
                float pv = __expf(sacc[nt][r] - mnew);
                pr[nt][r] = pv; rs += pv;
            }
            #pragma unroll
            for (int off = 1; off < 16; off <<= 1)
                rs += __shfl_xor(rs, off, 64);
            l_run[r] = fmaf(l_run[r], alpha, rs);
            #pragma unroll
            for (int ht = 0; ht < 4; ht++)
                oacc[ht][r] = oacc[ht][r] * alpha;
        }

        // P -> ps (f16, wave-private rows; same-wave RAW, no barrier needed)
        #pragma unroll
        for (int nt = 0; nt < 4; nt++)
            #pragma unroll
            for (int r = 0; r < 4; r++) {
                float pv = pr[nt][r];
                float pn = __shfl_xor(pv, 1, 64);
                if (!(l15 & 1)) {
                    f16x2 pk = { (_Float16)pv, (_Float16)pn };
                    *(f16x2*)&ps[(w * 16 + quad * 4 + r) * SQP + nt * 16 + l15] = pk;
                }
            }

        // O += P V  (8 MFMA), vsT read with matching XOR swizzle
        #pragma unroll
        for (int sc = 0; sc < 2; sc++) {
            f16x8 ap = *(const f16x8*)&ps[(w * 16 + l15) * SQP + sc * 32 + quad * 8];
            int sq = sc * 32 + quad * 8;
            #pragma unroll
            for (int ht = 0; ht < 4; ht++) {
                int h  = ht * 16 + l15;
                int xb = (((sq >> 3) ^ (h >> 3)) << 3);
                f16x8 bv = *(const f16x8*)&vsT[cur][h * SQP + xb];
                oacc[ht] = __builtin_amdgcn_mfma_f32_16x16x32_f16(ap, bv, oacc[ht], 0, 0, 0);
            }
        }

        if (jt + 1 < nst) stage(cur ^ 1);
        __syncthreads();
    }

    #pragma unroll
    for (int r = 0; r < 4; r++) {
        float inv  = 1.0f / l_run[r];
        int   trow = t0 + w * 16 + quad * 4 + r;
        float* op  = out + ((size_t)b * Tn + trow) * Hn;
        #pragma unroll
        for (int ht = 0; ht < 4; ht++)
            op[ht * 16 + l15] = oacc[ht][r] * inv;
    }
}

extern "C" void kernel_launch(void* const* d_in, const int* in_sizes, int n_in,
                              void* d_out, int out_size, void* d_ws, size_t ws_size,
                              hipStream_t stream) {
    const float* x  = (const float*)d_in[0];
    const float* Wq = (const float*)d_in[1];
    const float* Wk = (const float*)d_in[2];
    const float* Wv = (const float*)d_in[3];

    const size_t qkvN = (size_t)BTn * Hn;
    _Float16* qh = (_Float16*)d_ws;
    _Float16* kh = qh + qkvN;
    _Float16* vh = kh + qkvN;
    _Float16* Wt = vh + qkvN;                     // [192][1024] f16

    prep_w_kernel<<<48, 256, 0, stream>>>(Wq, Wk, Wv, Wt);
    proj_kernel<<<BTn / 32, 256, 0, stream>>>(x, Wt, qh, kh, vh);
    attn_kernel<<<512, 128, 0, stream>>>(qh, kh, vh, (float*)d_out);
}

// Round 4
// 162.703 us; speedup vs baseline: 2.7885x; 1.1705x over previous
//
#include <hip/hip_runtime.h>
#include <cmath>

#define Tn  2048
#define Cn  1024
#define Hn  64
#define BTn 16384

typedef _Float16 f16x8 __attribute__((ext_vector_type(8)));
typedef _Float16 f16x4 __attribute__((ext_vector_type(4)));
typedef _Float16 f16x2 __attribute__((ext_vector_type(2)));
typedef float    f32x4 __attribute__((ext_vector_type(4)));

// ---------------------------------------------------------------------------
// prep: transpose Wq|Wk|Wv (each [Cn][64] fp32) into Wt[192][Cn] f16
// ---------------------------------------------------------------------------
__global__ __launch_bounds__(256) void prep_w_kernel(
    const float* __restrict__ Wq, const float* __restrict__ Wk,
    const float* __restrict__ Wv, _Float16* __restrict__ Wt)
{
    __shared__ float ts[64][65];
    const int blk = blockIdx.x;          // 48 = 3 proj * 16 c-tiles
    const int p   = blk >> 4;
    const int c0  = (blk & 15) * 64;
    const float* __restrict__ W = (p == 0) ? Wq : (p == 1) ? Wk : Wv;
    const int tid = threadIdx.x;
    #pragma unroll
    for (int it = 0; it < 16; it++) {
        int idx = tid + it * 256;
        int c = idx >> 6, n = idx & 63;
        ts[c][n] = W[(size_t)(c0 + c) * Hn + n];
    }
    __syncthreads();
    #pragma unroll
    for (int it = 0; it < 16; it++) {
        int idx = tid + it * 256;
        int n = idx >> 6, c = idx & 63;
        Wt[(size_t)(p * 64 + n) * Cn + c0 + c] = (_Float16)ts[c][n];
    }
}

// ---------------------------------------------------------------------------
// proj: barrier-free K-loop. Block = 32 rows x all 192 out-cols. 4 waves;
// wave w owns n-range [w*48, w*48+48) x 32 rows (2m x 3n MFMA tiles).
// x-tile staged to LDS ONCE (f16, row stride 1032 = 4 mod 32 dwords:
// conflict-free quarter-wave frag reads); W B-frags read directly from
// global (Wt is 384 KB, L2-resident) interleaved with MFMA - no barriers.
// Epilogue: RoPE on q/k (q pre-scaled H^-1/2), v written TRANSPOSED
// vT[b][h][t] so attn can read PV B-frags straight from global.
// ---------------------------------------------------------------------------
#define XSP 1032

__global__ __launch_bounds__(256) void proj_kernel(
    const float* __restrict__ x, const _Float16* __restrict__ Wt,
    _Float16* __restrict__ qh, _Float16* __restrict__ kh, _Float16* __restrict__ vT)
{
    __shared__ _Float16 xs[32 * XSP];    // 66 KB -> 2 blocks/CU
    const int row0 = blockIdx.x * 32;
    const int tid  = threadIdx.x;
    const int wave = tid >> 6, lane = tid & 63;
    const int quad = lane >> 4, l15 = lane & 15;

    // Stage x (32 rows x 1024 fp32 -> f16) once. Coalesced float4 reads.
    #pragma unroll 8
    for (int it = 0; it < 32; it++) {
        int idx = tid + it * 256;        // row = idx>>8, col4 = idx&255
        int r = idx >> 8, c4 = idx & 255;
        float4 xv = *(const float4*)&x[(size_t)(row0 + r) * Cn + c4 * 4];
        f16x4 hv = { (_Float16)xv.x, (_Float16)xv.y, (_Float16)xv.z, (_Float16)xv.w };
        *(f16x4*)&xs[r * XSP + c4 * 4] = hv;
    }
    __syncthreads();                     // the only barrier

    f32x4 acc[2][3] = {};
    const _Float16* __restrict__ wb = Wt + (size_t)(wave * 48 + l15) * Cn + quad * 8;

    #pragma unroll 4
    for (int kc = 0; kc < Cn; kc += 32) {
        f16x8 b0 = *(const f16x8*)&wb[kc];
        f16x8 b1 = *(const f16x8*)&wb[16 * Cn + kc];
        f16x8 b2 = *(const f16x8*)&wb[32 * Cn + kc];
        f16x8 a0 = *(const f16x8*)&xs[(     l15) * XSP + kc + quad * 8];
        f16x8 a1 = *(const f16x8*)&xs[(16 + l15) * XSP + kc + quad * 8];
        acc[0][0] = __builtin_amdgcn_mfma_f32_16x16x32_f16(a0, b0, acc[0][0], 0, 0, 0);
        acc[1][0] = __builtin_amdgcn_mfma_f32_16x16x32_f16(a1, b0, acc[1][0], 0, 0, 0);
        acc[0][1] = __builtin_amdgcn_mfma_f32_16x16x32_f16(a0, b1, acc[0][1], 0, 0, 0);
        acc[1][1] = __builtin_amdgcn_mfma_f32_16x16x32_f16(a1, b1, acc[1][1], 0, 0, 0);
        acc[0][2] = __builtin_amdgcn_mfma_f32_16x16x32_f16(a0, b2, acc[0][2], 0, 0, 0);
        acc[1][2] = __builtin_amdgcn_mfma_f32_16x16x32_f16(a1, b2, acc[1][2], 0, 0, 0);
    }

    // Epilogue
    const int bidx = row0 >> 11;
    #pragma unroll
    for (int nt = 0; nt < 3; nt++) {
        const int n = wave * 48 + nt * 16 + l15;
        const int p = n >> 6;            // uniform per (wave,nt)
        const int h = n & 63;
        if (p < 2) {                     // q or k: RoPE
            _Float16* __restrict__ outb = (p == 0) ? qh : kh;
            const float invf = __expf(-0.2878231366242557f * (float)(h >> 1));
            #pragma unroll
            for (int mt = 0; mt < 2; mt++) {
                #pragma unroll
                for (int r = 0; r < 4; r++) {
                    int   row = row0 + mt * 16 + quad * 4 + r;
                    float val = acc[mt][nt][r];
                    float partner = __shfl_xor(val, 1, 64);
                    float ang = (float)(row & (Tn - 1)) * invf;
                    float sv, cv;
                    __sincosf(ang, &sv, &cv);
                    float res = (h & 1) ? fmaf(val, cv,  partner * sv)
                                        : fmaf(val, cv, -partner * sv);
                    if (p == 0) res *= 0.125f;
                    float resn = __shfl_xor(res, 1, 64);
                    if (!(l15 & 1)) {
                        f16x2 pk = { (_Float16)res, (_Float16)resn };
                        *(f16x2*)&outb[(size_t)row * Hn + h] = pk;
                    }
                }
            }
        } else {                         // v: store transposed vT[b][h][t]
            #pragma unroll
            for (int mt = 0; mt < 2; mt++) {
                int t = (row0 & (Tn - 1)) + mt * 16 + quad * 4;
                f16x4 pv = { (_Float16)acc[mt][nt][0], (_Float16)acc[mt][nt][1],
                             (_Float16)acc[mt][nt][2], (_Float16)acc[mt][nt][3] };
                *(f16x4*)&vT[((size_t)bidx * Hn + h) * Tn + t] = pv;
            }
        }
    }
}

// ---------------------------------------------------------------------------
// attn: barrier-free flash loop. QT=16, STL=64, 128 thr = 2 waves; each wave
// processes alternate s-tiles (jt = w, w+2, ...) with its own online-softmax
// state; one barrier + LDS merge at the end. K and vT B-frags read directly
// from global (L2: batch working set 768 KB, XCD-affine via b = blk&7).
// qt permuted so each CU's 4 resident blocks have constant total work.
// ---------------------------------------------------------------------------
#define PSP 72

__global__ __launch_bounds__(128) void attn_kernel(
    const _Float16* __restrict__ qh, const _Float16* __restrict__ kh,
    const _Float16* __restrict__ vT, float* __restrict__ out)
{
    __shared__ _Float16 ps[2][16 * PSP];     // wave-private P transpose
    __shared__ float ocomb[2][16][65];
    __shared__ float mlcomb[2][2][16];       // [wave][m|l][row]

    const int blk = blockIdx.x;
    const int b   = blk & 7;                 // batch == XCD affinity
    const int j   = blk >> 3;                // 0..127
    const int jm  = j & 31, g = j >> 5;      // complement permutation:
    const int qt  = (g == 0) ? (127 - jm)    // per-CU resident set sums const
                  : (g == 1) ? (64 + jm)
                  : (g == 2) ? (63 - jm) : jm;
    const int t0  = qt * 16;
    const int tid = threadIdx.x;
    const int w = tid >> 6, lane = tid & 63;
    const int quad = lane >> 4, l15 = lane & 15;

    const _Float16* __restrict__ qb = qh + (size_t)b * Tn * Hn;
    const _Float16* __restrict__ kb = kh + (size_t)b * Tn * Hn;
    const _Float16* __restrict__ vb = vT + (size_t)b * Hn * Tn;

    // Q A-frags: held in registers for the whole loop
    const f16x8 aq0 = *(const f16x8*)&qb[(size_t)(t0 + l15) * Hn +      quad * 8];
    const f16x8 aq1 = *(const f16x8*)&qb[(size_t)(t0 + l15) * Hn + 32 + quad * 8];

    float m_run[4], l_run[4];
    f32x4 oacc[4] = {};
    #pragma unroll
    for (int r = 0; r < 4; r++) { m_run[r] = -1e30f; l_run[r] = 0.0f; }

    const int nst = (t0 + 16 + 63) >> 6;
    for (int jt = w; jt < nst; jt += 2) {
        const int s0 = jt * 64;

        // K B-frags direct from global (16 rows x 64B per load instr)
        f16x8 kf[4][2];
        #pragma unroll
        for (int nt = 0; nt < 4; nt++) {
            const _Float16* kp = &kb[(size_t)(s0 + nt * 16 + l15) * Hn + quad * 8];
            kf[nt][0] = *(const f16x8*)kp;
            kf[nt][1] = *(const f16x8*)(kp + 32);
        }
        f32x4 sacc[4];
        #pragma unroll
        for (int nt = 0; nt < 4; nt++) {
            f32x4 z = {};
            z = __builtin_amdgcn_mfma_f32_16x16x32_f16(aq0, kf[nt][0], z, 0, 0, 0);
            z = __builtin_amdgcn_mfma_f32_16x16x32_f16(aq1, kf[nt][1], z, 0, 0, 0);
            sacc[nt] = z;
        }

        // vT B-frags: issue before softmax (independent), consumed by PV
        f16x8 vf[2][4];
        #pragma unroll
        for (int sc = 0; sc < 2; sc++)
            #pragma unroll
            for (int ht = 0; ht < 4; ht++)
                vf[sc][ht] = *(const f16x8*)&vb[(size_t)(ht * 16 + l15) * Tn
                                                + s0 + sc * 32 + quad * 8];

        if (jt == nst - 1) {             // causal mask: only diagonal tile
            #pragma unroll
            for (int nt = 0; nt < 4; nt++)
                #pragma unroll
                for (int r = 0; r < 4; r++) {
                    int scol = s0 + nt * 16 + l15;
                    int trow = t0 + quad * 4 + r;
                    if (scol > trow) sacc[nt][r] = -1e30f;
                }
        }

        // online softmax (rows = quad*4+r; reduce over the 16 l15 lanes)
        float pr[4][4];
        #pragma unroll
        for (int r = 0; r < 4; r++) {
            float mx = fmaxf(fmaxf(sacc[0][r], sacc[1][r]),
                             fmaxf(sacc[2][r], sacc[3][r]));
            #pragma unroll
            for (int off = 1; off < 16; off <<= 1)
                mx = fmaxf(mx, __shfl_xor(mx, off, 64));
            float mnew  = fmaxf(m_run[r], mx);
            float alpha = __expf(m_run[r] - mnew);
            m_run[r] = mnew;
            float rs = 0.0f;
            #pragma unroll
            for (int nt = 0; nt < 4; nt++) {
                float pv = __expf(sacc[nt][r] - mnew);
                pr[nt][r] = pv; rs += pv;
            }
            #pragma unroll
            for (int off = 1; off < 16; off <<= 1)
                rs += __shfl_xor(rs, off, 64);
            l_run[r] = fmaf(l_run[r], alpha, rs);
            #pragma unroll
            for (int ht = 0; ht < 4; ht++)
                oacc[ht][r] = oacc[ht][r] * alpha;
        }

        // P -> ps (wave-private; same-wave RAW, no barrier)
        #pragma unroll
        for (int nt = 0; nt < 4; nt++)
            #pragma unroll
            for (int r = 0; r < 4; r++) {
                float pv = pr[nt][r];
                float pn = __shfl_xor(pv, 1, 64);
                if (!(l15 & 1)) {
                    f16x2 pk = { (_Float16)pv, (_Float16)pn };
                    *(f16x2*)&ps[w][(quad * 4 + r) * PSP + nt * 16 + l15] = pk;
                }
            }

        // O += P V  (8 MFMA, B-frags already in registers)
        #pragma unroll
        for (int sc = 0; sc < 2; sc++) {
            f16x8 ap = *(const f16x8*)&ps[w][l15 * PSP + sc * 32 + quad * 8];
            #pragma unroll
            for (int ht = 0; ht < 4; ht++)
                oacc[ht] = __builtin_amdgcn_mfma_f32_16x16x32_f16(ap, vf[sc][ht],
                                                                  oacc[ht], 0, 0, 0);
        }
    }

    // Write partials, barrier, merge the two waves' online-softmax states.
    #pragma unroll
    for (int r = 0; r < 4; r++) {
        #pragma unroll
        for (int ht = 0; ht < 4; ht++)
            ocomb[w][quad * 4 + r][ht * 16 + l15] = oacc[ht][r];
        if (l15 == 0) {
            mlcomb[w][0][quad * 4 + r] = m_run[r];
            mlcomb[w][1][quad * 4 + r] = l_run[r];
        }
    }
    __syncthreads();

    // wave w finalizes h-range [w*32, w*32+32): 2 rows x 32 h per pass
    #pragma unroll
    for (int rp = 0; rp < 8; rp++) {
        int row = rp * 2 + (lane >> 5);
        int h   = w * 32 + (lane & 31);
        float m0 = mlcomb[0][0][row], m1 = mlcomb[1][0][row];
        float mm = fmaxf(m0, m1);
        float a0 = __expf(m0 - mm), a1 = __expf(m1 - mm);
        float ll = mlcomb[0][1][row] * a0 + mlcomb[1][1][row] * a1;
        float ov = (ocomb[0][row][h] * a0 + ocomb[1][row][h] * a1) / ll;
        out[((size_t)b * Tn + t0 + row) * Hn + h] = ov;
    }
}

extern "C" void kernel_launch(void* const* d_in, const int* in_sizes, int n_in,
                              void* d_out, int out_size, void* d_ws, size_t ws_size,
                              hipStream_t stream) {
    const float* x  = (const float*)d_in[0];
    const float* Wq = (const float*)d_in[1];
    const float* Wk = (const float*)d_in[2];
    const float* Wv = (const float*)d_in[3];

    const size_t qkvN = (size_t)BTn * Hn;
    _Float16* qh = (_Float16*)d_ws;
    _Float16* kh = qh + qkvN;
    _Float16* vT = kh + qkvN;                     // [8][64][2048] transposed
    _Float16* Wt = vT + qkvN;                     // [192][1024] f16

    prep_w_kernel<<<48, 256, 0, stream>>>(Wq, Wk, Wv, Wt);
    proj_kernel<<<BTn / 32, 256, 0, stream>>>(x, Wt, qh, kh, vT);
    attn_kernel<<<1024, 128, 0, stream>>>(qh, kh, vT, (float*)d_out);
}